// Round 15
// baseline (51.401 us; speedup 1.0000x reference)
//
#include <hip/hip_runtime.h>
#include <hip/hip_fp16.h>
#include <math.h>

#define TT 8192
#define FF 64
#define TILE 32
#define HALO 50
#define ROWS (TILE + HALO)   // 82
#define XSTR 72              // f16 row stride for xsH
#define PSTR 68              // f32 plane row stride (272B = 17*16: 16B-aligned rows)

typedef float f32x2 __attribute__((ext_vector_type(2)));
typedef float f32x4 __attribute__((ext_vector_type(4)));
typedef _Float16 f16x8 __attribute__((ext_vector_type(8)));
typedef unsigned int u32x4 __attribute__((ext_vector_type(4)));
typedef unsigned int u32x2 __attribute__((ext_vector_type(2)));

__device__ __forceinline__ float rcpf(float x) { return __builtin_amdgcn_rcpf(x); }

// ---- prep: wsmH[i*64+j] = f16 softmax(W)[i][j] (ROW-major); pwB = f16 MFMA B-frags ----
// B-frag (mfma_f32_16x16x32_f16): lane holds B[k=(lane>>4)*8+q][col=lane&15],
// B[k][col] = PW[n*16+col][k]; slot (n*2+kt)*64+lane.  (validated R12-R14)
__global__ void prep_kernel(const float* __restrict__ W, const float* __restrict__ PW,
                            __half* __restrict__ wsmH, u32x4* __restrict__ pwB) {
    const int lane = threadIdx.x;
    const int wv   = threadIdx.y;
    const int tid  = wv * 64 + lane;
    for (int it = 0; it < 16; ++it) {
        const int r = wv * 16 + it;
        float v = W[r * 64 + lane];
        float m = v;
        #pragma unroll
        for (int off = 32; off >= 1; off >>= 1)
            m = fmaxf(m, __shfl_xor(m, off, 64));
        float e = __expf(v - m);
        float s = e;
        #pragma unroll
        for (int off = 32; off >= 1; off >>= 1)
            s += __shfl_xor(s, off, 64);
        wsmH[r * 64 + lane] = __float2half(e * rcpf(s));   // row-major now
    }
    for (int s = tid; s < 512; s += 256) {
        const int n2 = s >> 6;
        const int ln = s & 63;
        const int i  = (n2 >> 1) * 16 + (ln & 15);
        const int k0 = (n2 & 1) * 32 + (ln >> 4) * 8;
        u32x4 frag;
        #pragma unroll
        for (int w = 0; w < 4; ++w) {
            const unsigned lo = __half_as_ushort(__float2half_rn(PW[i * 64 + k0 + 2 * w]));
            const unsigned hi = __half_as_ushort(__float2half_rn(PW[i * 64 + k0 + 2 * w + 1]));
            frag[w] = lo | (hi << 16);
        }
        pwB[s] = frag;
    }
}

// ---- fused main: 512 thr / 8 waves, 32-row tile, 4 blocks/CU = 32 waves/CU ----
__global__ __launch_bounds__(512, 8)
void mcao_main(const float* __restrict__ x,
               const __half* __restrict__ wsmH,
               const u32x4* __restrict__ pwB,
               const float* __restrict__ pb,
               const float* __restrict__ kap,
               const float* __restrict__ coeffs,
               float* __restrict__ out,
               float* __restrict__ memout) {
    // LDS 37408 B -> 4 blocks/CU:
    //   [0, 11808)      xsH f16 [82][72]   (dead after bar2)
    //   [0, 8448)       P2  f32 [64][33]   (after j-loop, overlays xsH)
    //   [11808, 20512)  tS  f32 [32][68]   tanh[row][feat]
    //   [20512, 29216)  uS  f32 [32][68]   e^-|x|[row][feat]
    //   [29216, 37408)  wT  f16 [64][64]   softmax(W)[i][j] row-major
    __shared__ __align__(16) char smem[37408];
    __half* xsH = (__half*)smem;
    float*  P2  = (float*)smem;
    float*  tS  = (float*)(smem + 11808);
    float*  uS  = (float*)(smem + 20512);
    __half* wT  = (__half*)(smem + 29216);

    const int tid  = threadIdx.x;
    const int lane = tid & 63;
    const int wv   = tid >> 6;              // 0..7

    // XCD-aware bijective swizzle: 1024 blocks -> 128 consecutive tiles per XCD
    const int sw = ((int)blockIdx.x & 7) * 128 + ((int)blockIdx.x >> 3);
    const int b  = sw >> 8;                 // 0..3
    const int t0 = (sw & 255) * TILE;
    const float* xb = x + (size_t)b * TT * FF;

    // ---- stage xsH rows [t0-50, t0+32) as f16 (zero-pad t<0), and wT ----
    for (int i4 = tid; i4 < ROWS * 16; i4 += 512) {
        const int s = i4 >> 4, f4 = i4 & 15, t = t0 - HALO + s;
        f32x4 v = {0.f, 0.f, 0.f, 0.f};
        if (t >= 0) v = *(const f32x4*)(xb + (size_t)t * 64 + f4 * 4);
        __half hv[4];
        #pragma unroll
        for (int q = 0; q < 4; ++q) hv[q] = __float2half_rn(v[q]);
        *(u32x2*)(&xsH[s * XSTR + f4 * 4]) = *(u32x2*)hv;
    }
    ((f32x4*)wT)[tid] = ((const f32x4*)wsmH)[tid];
    __syncthreads();                                    // bar1

    // ---- FIR: wave owns rows 4wv..4wv+3 (lane = feature) ----
    float macc[4] = {0.f, 0.f, 0.f, 0.f};
    #pragma unroll
    for (int s = 0; s < 54; ++s) {
        const float xv = __half2float(xsH[(4 * wv + s) * XSTR + lane]);
        #pragma unroll
        for (int r = 0; r < 4; ++r) {
            const int k = r + 50 - s;
            if (0 <= k && k <= 50) macc[r] = fmaf(coeffs[k], xv, macc[r]);
        }
    }
    #pragma unroll
    for (int r = 0; r < 4; ++r)
        memout[(size_t)(b * TT + t0 + 4 * wv + r) * 64 + lane] = macc[r];

    // ---- proj via MFMA: wave -> (mt = wv>>2, nt = wv&3) ----
    const int mt = wv >> 2, nt = wv & 3;
    const int marow = HALO + mt * 16 + (lane & 15);
    const int kcol = (lane >> 4) * 8;
    f32x4 cfr = {0.f, 0.f, 0.f, 0.f};
    #pragma unroll
    for (int kt = 0; kt < 2; ++kt) {
        const f16x8 afr = *(const f16x8*)(&xsH[marow * XSTR + kt * 32 + kcol]);
        const f16x8 bfr = __builtin_bit_cast(f16x8, pwB[(nt * 2 + kt) * 64 + lane]);
        cfr = __builtin_amdgcn_mfma_f32_16x16x32_f16(afr, bfr, cfr, 0, 0, 0);
    }

    // ---- extraction: thread -> (erow=tid>>4, feats (tid&15)*4..+3) ----
    const int erow = tid >> 4, f0 = (tid & 15) * 4;
    __half hx[4];
    *(u32x2*)hx = *(const u32x2*)(&xsH[(HALO + erow) * XSTR + f0]);
    f32x4 tq, uq;
    #pragma unroll
    for (int q = 0; q < 4; ++q) {
        const float xi = __half2float(hx[q]);
        tq[q] = fmaf(-2.f, rcpf(__expf(2.f * xi) + 1.f), 1.f);  // tanh
        uq[q] = __expf(-fabsf(xi));                             // e^-|x|
    }
    __syncthreads();                                    // bar2 (xsH dead after this phase's reads)
    *(f32x4*)(&tS[erow * PSTR + f0]) = tq;
    *(f32x4*)(&uS[erow * PSTR + f0]) = uq;
    __syncthreads();                                    // bar3 (planes ready)

    // ---- coupling: lane = (h=lane>>5, r=lane&31); feats ib..ib+3 ----
    const int r  = lane & 31;
    const int h  = lane >> 5;
    const int ib = wv * 8 + h * 4;
    const f32x4 ti4 = *(const f32x4*)(&tS[r * PSTR + ib]);
    const f32x4 ui4 = *(const f32x4*)(&uS[r * PSTR + ib]);
    const f32x2 tiP0 = {ti4.x, ti4.y}, tiP1 = {ti4.z, ti4.w};
    const f32x2 uiP0 = {ui4.x, ui4.y}, uiP1 = {ui4.z, ui4.w};

    f32x2 cac0 = {0.f, 0.f}, cac1 = {0.f, 0.f};
    const f32x2 one2 = {1.f, 1.f};
    #pragma unroll 4
    for (int c = 0; c < 16; ++c) {
        const int j0 = c * 4;
        const f32x4 t4 = *(const f32x4*)(&tS[r * PSTR + j0]);   // 4 j's, one b128
        const f32x4 u4 = *(const f32x4*)(&uS[r * PSTR + j0]);
        __half w0[4], w1[4], w2[4], w3[4];                      // w[i][j0..j0+3]
        *(u32x2*)w0 = *(const u32x2*)(&wT[(ib + 0) * 64 + j0]);
        *(u32x2*)w1 = *(const u32x2*)(&wT[(ib + 1) * 64 + j0]);
        *(u32x2*)w2 = *(const u32x2*)(&wT[(ib + 2) * 64 + j0]);
        *(u32x2*)w3 = *(const u32x2*)(&wT[(ib + 3) * 64 + j0]);
        #pragma unroll
        for (int jj = 0; jj < 4; ++jj) {
            const f32x2 tjj = {t4[jj], t4[jj]};
            const f32x2 ujj = {u4[jj], u4[jj]};
            {
                const f32x2 d1  = __builtin_elementwise_fma(-tiP0, tjj, one2);
                const f32x2 d2  = __builtin_elementwise_fma( uiP0, ujj, one2);
                const f32x2 den = d1 * d2;
                f32x2 rr; rr.x = rcpf(den.x); rr.y = rcpf(den.y);
                const f32x2 s = (tiP0 - tjj) * rr;
                cac0.x = fmaf(__half2float(w0[jj]), s.x, cac0.x);   // fma_mix
                cac0.y = fmaf(__half2float(w1[jj]), s.y, cac0.y);
            }
            {
                const f32x2 d1  = __builtin_elementwise_fma(-tiP1, tjj, one2);
                const f32x2 d2  = __builtin_elementwise_fma( uiP1, ujj, one2);
                const f32x2 den = d1 * d2;
                f32x2 rr; rr.x = rcpf(den.x); rr.y = rcpf(den.y);
                const f32x2 s = (tiP1 - tjj) * rr;
                cac1.x = fmaf(__half2float(w2[jj]), s.x, cac1.x);
                cac1.y = fmaf(__half2float(w3[jj]), s.y, cac1.y);
            }
        }
    }

    // ---- proj C-frag -> P2 (xsH dead; no pre-barrier needed) ----
    {
        const int ic = nt * 16 + (lane & 15);
        const int rb = mt * 16 + (lane >> 4) * 4;
        #pragma unroll
        for (int reg = 0; reg < 4; ++reg)
            P2[ic * 33 + rb + reg] = cfr[reg];
    }
    __syncthreads();                                    // bar4 (proj visible)

    // ---- epilogue RMW: P2 <- 0.4c + 0.3(proj+pb)ksum ----
    const float kappa = kap[0];
    const float ksum  = (1.f - __expf(-kappa * (float)(t0 + r + 1))) *
                        rcpf(1.f - __expf(-kappa));
    const f32x4 pbv = *(const f32x4*)(pb + ib);
    #pragma unroll
    for (int q = 0; q < 4; ++q) {
        const float cv = (q & 1) ? ((q >> 1) ? cac1.y : cac0.y)
                                 : ((q >> 1) ? cac1.x : cac0.x);
        const int idx = (ib + q) * 33 + r;
        P2[idx] = fmaf(0.4f, cv, 0.3f * (P2[idx] + pbv[q]) * ksum);
    }
    __syncthreads();                                    // bar5

    // ---- final store: wave rows 4wv..4wv+3, lane = feature (coalesced) ----
    #pragma unroll
    for (int rr2 = 0; rr2 < 4; ++rr2) {
        const int row = 4 * wv + rr2;
        out[(size_t)(b * TT + t0 + row) * 64 + lane] =
            fmaf(0.3f, macc[rr2], P2[lane * 33 + row]);  // (lane+row)%32: free
    }
}

extern "C" void kernel_launch(void* const* d_in, const int* in_sizes, int n_in,
                              void* d_out, int out_size, void* d_ws, size_t ws_size,
                              hipStream_t stream) {
    const float* x   = (const float*)d_in[0];
    const float* W   = (const float*)d_in[1];
    const float* PW  = (const float*)d_in[2];
    const float* pb  = (const float*)d_in[3];
    const float* kap = (const float*)d_in[4];
    const float* cf  = (const float*)d_in[5];

    float* out    = (float*)d_out;
    float* memout = out + (size_t)4 * TT * FF;

    __half* wsmH = (__half*)d_ws;                        // 8 KB
    u32x4*  pwB  = (u32x4*)((char*)d_ws + 8192);         // 8 KB

    hipLaunchKernelGGL(prep_kernel, dim3(1), dim3(64, 4), 0, stream, W, PW, wsmH, pwB);
    hipLaunchKernelGGL(mcao_main, dim3(4 * (TT / TILE)), dim3(512), 0, stream,
                       x, wsmH, pwB, pb, kap, cf, out, memout);
}

// Round 16
// 45.776 us; speedup vs baseline: 1.1229x; 1.1229x over previous
//
#include <hip/hip_runtime.h>
#include <hip/hip_fp16.h>
#include <math.h>

#define TT 8192
#define FF 64
#define TILE 32
#define HALO 50
#define ROWS 82              // TILE + HALO
#define XSTR 72              // f16 row stride for xsH

typedef float f32x2 __attribute__((ext_vector_type(2)));
typedef float f32x4 __attribute__((ext_vector_type(4)));
typedef _Float16 f16x8 __attribute__((ext_vector_type(8)));
typedef unsigned int u32x4 __attribute__((ext_vector_type(4)));
typedef unsigned int u32x2 __attribute__((ext_vector_type(2)));

__device__ __forceinline__ float rcpf(float x) { return __builtin_amdgcn_rcpf(x); }

// ---- prep: wsmH[j*64+i] = f16 softmax(W)[i][j]; pwB = f16 MFMA B-frags of PW;
//      cpad[57]: cpad[q] = coeffs[q-3] for 0<=q-3<=50 else 0  (FIR zero-pad table)
__global__ void prep_kernel(const float* __restrict__ W, const float* __restrict__ PW,
                            const float* __restrict__ C,
                            __half* __restrict__ wsmH, u32x4* __restrict__ pwB,
                            float* __restrict__ cpad) {
    const int lane = threadIdx.x;
    const int wv   = threadIdx.y;
    const int tid  = wv * 64 + lane;
    for (int it = 0; it < 16; ++it) {
        const int r = wv * 16 + it;
        float v = W[r * 64 + lane];
        float m = v;
        #pragma unroll
        for (int off = 32; off >= 1; off >>= 1)
            m = fmaxf(m, __shfl_xor(m, off, 64));
        float e = __expf(v - m);
        float s = e;
        #pragma unroll
        for (int off = 32; off >= 1; off >>= 1)
            s += __shfl_xor(s, off, 64);
        wsmH[lane * 64 + r] = __float2half(e * rcpf(s));   // [j][i]
    }
    for (int s = tid; s < 512; s += 256) {
        const int n2 = s >> 6;
        const int ln = s & 63;
        const int i  = (n2 >> 1) * 16 + (ln & 15);
        const int k0 = (n2 & 1) * 32 + (ln >> 4) * 8;
        u32x4 frag;
        #pragma unroll
        for (int w = 0; w < 4; ++w) {
            const unsigned lo = __half_as_ushort(__float2half_rn(PW[i * 64 + k0 + 2 * w]));
            const unsigned hi = __half_as_ushort(__float2half_rn(PW[i * 64 + k0 + 2 * w + 1]));
            frag[w] = lo | (hi << 16);
        }
        pwB[s] = frag;
    }
    if (tid < 57) {
        const int k = tid - 3;
        cpad[tid] = (k >= 0 && k <= 50) ? C[k] : 0.f;
    }
}

// ---- fused main: 512 thr / 8 waves, 32-row tile; staging+planes, FIR-in-j-loop ----
__global__ __launch_bounds__(512, 8)
void mcao_main(const float* __restrict__ x,
               const __half* __restrict__ wsmH,
               const u32x4* __restrict__ pwB,
               const float* __restrict__ cpad,
               const float* __restrict__ pb,
               const float* __restrict__ kap,
               float* __restrict__ out,
               float* __restrict__ memout) {
    // LDS 37408 B -> 4 blocks/CU:
    //   [0, 11808)      xsH f16 [82][72]   (dead after megaloop)
    //   [0, 8448)       P2  f32 [64][33]   (overlays xsH after bar2)
    //   [11808, 29216)  tuS f32x2 [64][34] {t,u}[feat][row]
    //   [29216, 37408)  wT  f16 [64][64]   softmax(W) at [j*64+i]
    __shared__ __align__(16) char smem[37408];
    __half* xsH = (__half*)smem;
    float*  P2  = (float*)smem;
    f32x2*  tuS = (f32x2*)(smem + 11808);
    __half* wT  = (__half*)(smem + 29216);

    const int tid  = threadIdx.x;
    const int lane = tid & 63;
    const int wv   = tid >> 6;              // 0..7

    // XCD-aware bijective swizzle: 1024 blocks -> 128 consecutive tiles per XCD
    const int sw = ((int)blockIdx.x & 7) * 128 + ((int)blockIdx.x >> 3);
    const int b  = sw >> 8;                 // 0..3
    const int t0 = (sw & 255) * TILE;
    const float* xb = x + (size_t)b * TT * FF;

    // ---- stage xsH (f16) + compute t/u planes inline (f32 source) + wT ----
    for (int i4 = tid; i4 < ROWS * 16; i4 += 512) {
        const int s = i4 >> 4, f4 = i4 & 15, t = t0 - HALO + s;
        f32x4 v = {0.f, 0.f, 0.f, 0.f};
        if (t >= 0) v = *(const f32x4*)(xb + (size_t)t * 64 + f4 * 4);
        __half hv[4];
        #pragma unroll
        for (int q = 0; q < 4; ++q) hv[q] = __float2half_rn(v[q]);
        *(u32x2*)(&xsH[s * XSTR + f4 * 4]) = *(u32x2*)hv;
        if (s >= HALO) {                    // tile row: planes from f32 x
            const int row = s - HALO;
            #pragma unroll
            for (int q = 0; q < 4; ++q) {
                f32x2 e;
                e.x = fmaf(-2.f, rcpf(__expf(2.f * v[q]) + 1.f), 1.f);  // tanh
                e.y = __expf(-fabsf(v[q]));                             // e^-|x|
                tuS[(f4 * 4 + q) * 34 + row] = e;
            }
        }
    }
    ((f32x4*)wT)[tid] = ((const f32x4*)wsmH)[tid];
    __syncthreads();                                    // bar1

    // ---- proj via MFMA (issued early; result consumed after megaloop) ----
    const int mt = wv >> 2, nt = wv & 3;
    const int marow = HALO + mt * 16 + (lane & 15);
    const int kcol  = (lane >> 4) * 8;
    f32x4 cfr = {0.f, 0.f, 0.f, 0.f};
    #pragma unroll
    for (int kt = 0; kt < 2; ++kt) {
        const f16x8 afr = *(const f16x8*)(&xsH[marow * XSTR + kt * 32 + kcol]);
        const f16x8 bfr = __builtin_bit_cast(f16x8, pwB[(nt * 2 + kt) * 64 + lane]);
        cfr = __builtin_amdgcn_mfma_f32_16x16x32_f16(afr, bfr, cfr, 0, 0, 0);
    }

    // ---- megaloop: coupling (lane=(h,r), feats ib..ib+3) + FIR (rows 4wv..4wv+3) ----
    const int r  = lane & 31;
    const int h  = lane >> 5;
    const int ib = wv * 8 + h * 4;
    f32x2 tiP0, tiP1, uiP0, uiP1;
    {
        const f32x2 e0 = tuS[(ib + 0) * 34 + r];
        const f32x2 e1 = tuS[(ib + 1) * 34 + r];
        const f32x2 e2 = tuS[(ib + 2) * 34 + r];
        const f32x2 e3 = tuS[(ib + 3) * 34 + r];
        tiP0.x = e0.x; tiP0.y = e1.x; uiP0.x = e0.y; uiP0.y = e1.y;
        tiP1.x = e2.x; tiP1.y = e3.x; uiP1.x = e2.y; uiP1.y = e3.y;
    }

    float macc[4] = {0.f, 0.f, 0.f, 0.f};
    f32x2 cac0 = {0.f, 0.f}, cac1 = {0.f, 0.f};
    const f32x2 one2 = {1.f, 1.f};
    const int firrow = 4 * wv;

    #pragma unroll 4
    for (int m = 0; m < 54; ++m) {
        const f32x2 e = tuS[m * 34 + r];                     // b64, 2-way free
        __half wh[4];
        *(u32x2*)wh = *(const u32x2*)(&wT[m * 64 + ib]);     // 2-addr b64 broadcast
        const float xv = __half2float(xsH[(firrow + m) * XSTR + lane]);  // FIR stream
        #pragma unroll
        for (int r2 = 0; r2 < 4; ++r2)
            macc[r2] = fmaf(cpad[r2 + 53 - m], xv, macc[r2]);   // s_load coeff
        const f32x2 tjj = {e.x, e.x}, ujj = {e.y, e.y};
        {
            const f32x2 d1  = __builtin_elementwise_fma(-tiP0, tjj, one2);
            const f32x2 d2  = __builtin_elementwise_fma( uiP0, ujj, one2);
            const f32x2 den = d1 * d2;
            f32x2 rr; rr.x = rcpf(den.x); rr.y = rcpf(den.y);
            const f32x2 s = (tiP0 - tjj) * rr;
            cac0.x = fmaf(__half2float(wh[0]), s.x, cac0.x);
            cac0.y = fmaf(__half2float(wh[1]), s.y, cac0.y);
        }
        {
            const f32x2 d1  = __builtin_elementwise_fma(-tiP1, tjj, one2);
            const f32x2 d2  = __builtin_elementwise_fma( uiP1, ujj, one2);
            const f32x2 den = d1 * d2;
            f32x2 rr; rr.x = rcpf(den.x); rr.y = rcpf(den.y);
            const f32x2 s = (tiP1 - tjj) * rr;
            cac1.x = fmaf(__half2float(wh[2]), s.x, cac1.x);
            cac1.y = fmaf(__half2float(wh[3]), s.y, cac1.y);
        }
    }
    #pragma unroll 4
    for (int m = 54; m < 64; ++m) {                          // coupling only
        const f32x2 e = tuS[m * 34 + r];
        __half wh[4];
        *(u32x2*)wh = *(const u32x2*)(&wT[m * 64 + ib]);
        const f32x2 tjj = {e.x, e.x}, ujj = {e.y, e.y};
        {
            const f32x2 d1  = __builtin_elementwise_fma(-tiP0, tjj, one2);
            const f32x2 d2  = __builtin_elementwise_fma( uiP0, ujj, one2);
            const f32x2 den = d1 * d2;
            f32x2 rr; rr.x = rcpf(den.x); rr.y = rcpf(den.y);
            const f32x2 s = (tiP0 - tjj) * rr;
            cac0.x = fmaf(__half2float(wh[0]), s.x, cac0.x);
            cac0.y = fmaf(__half2float(wh[1]), s.y, cac0.y);
        }
        {
            const f32x2 d1  = __builtin_elementwise_fma(-tiP1, tjj, one2);
            const f32x2 d2  = __builtin_elementwise_fma( uiP1, ujj, one2);
            const f32x2 den = d1 * d2;
            f32x2 rr; rr.x = rcpf(den.x); rr.y = rcpf(den.y);
            const f32x2 s = (tiP1 - tjj) * rr;
            cac1.x = fmaf(__half2float(wh[2]), s.x, cac1.x);
            cac1.y = fmaf(__half2float(wh[3]), s.y, cac1.y);
        }
    }

    // ---- memory-term store ----
    #pragma unroll
    for (int r2 = 0; r2 < 4; ++r2)
        memout[(size_t)(b * TT + t0 + firrow + r2) * 64 + lane] = macc[r2];

    __syncthreads();                                    // bar2 (xsH dead)

    // ---- proj C-frag -> P2 ----
    {
        const int ic = nt * 16 + (lane & 15);
        const int rb = mt * 16 + (lane >> 4) * 4;
        #pragma unroll
        for (int reg = 0; reg < 4; ++reg)
            P2[ic * 33 + rb + reg] = cfr[reg];
    }
    __syncthreads();                                    // bar3 (proj visible)

    // ---- epilogue RMW: P2 <- 0.4c + 0.3(proj+pb)ksum ----
    const float kappa = kap[0];
    const float ksum  = (1.f - __expf(-kappa * (float)(t0 + r + 1))) *
                        rcpf(1.f - __expf(-kappa));
    const f32x4 pbv = *(const f32x4*)(pb + ib);
    #pragma unroll
    for (int q = 0; q < 4; ++q) {
        const float cv = (q & 1) ? ((q >> 1) ? cac1.y : cac0.y)
                                 : ((q >> 1) ? cac1.x : cac0.x);
        const int idx = (ib + q) * 33 + r;
        P2[idx] = fmaf(0.4f, cv, 0.3f * (P2[idx] + pbv[q]) * ksum);
    }
    __syncthreads();                                    // bar4

    // ---- final store: wave rows 4wv..4wv+3, lane = feature (coalesced) ----
    #pragma unroll
    for (int rr2 = 0; rr2 < 4; ++rr2) {
        const int row = 4 * wv + rr2;
        out[(size_t)(b * TT + t0 + row) * 64 + lane] =
            fmaf(0.3f, macc[rr2], P2[lane * 33 + row]);  // (lane+row)%32: free
    }
}

extern "C" void kernel_launch(void* const* d_in, const int* in_sizes, int n_in,
                              void* d_out, int out_size, void* d_ws, size_t ws_size,
                              hipStream_t stream) {
    const float* x   = (const float*)d_in[0];
    const float* W   = (const float*)d_in[1];
    const float* PW  = (const float*)d_in[2];
    const float* pb  = (const float*)d_in[3];
    const float* kap = (const float*)d_in[4];
    const float* cf  = (const float*)d_in[5];

    float* out    = (float*)d_out;
    float* memout = out + (size_t)4 * TT * FF;

    __half* wsmH = (__half*)d_ws;                        // 8 KB
    u32x4*  pwB  = (u32x4*)((char*)d_ws + 8192);         // 8 KB
    float*  cpad = (float*)((char*)d_ws + 16384);        // 228 B

    hipLaunchKernelGGL(prep_kernel, dim3(1), dim3(64, 4), 0, stream,
                       W, PW, cf, wsmH, pwB, cpad);
    hipLaunchKernelGGL(mcao_main, dim3(4 * (TT / TILE)), dim3(512), 0, stream,
                       x, wsmH, pwB, cpad, pb, kap, out, memout);
}